// Round 3
// baseline (212.344 us; speedup 1.0000x reference)
//
#include <hip/hip_runtime.h>
#include <stdint.h>

// VectorQuantize: x (8,256,32,32) f32, embed_w (4096,256) f32
// M = 8192 rows, K = 4096 codes, d = 256
// out (floats): [0,2097152) x_q (b,c,h,w); [2097152] loss; [2097153,2105345) embed_ind
//
// Split-fp16 MFMA GEMM (hi+lo planes, 3 MFMAs per fp32-equiv dot, e scaled 2^12).
// Round 3: 32x32x16 MFMA + 256x128 block tiles (LDS-read traffic per MAC -25%,
// one 32x32 MFMA saturates the CU matrix pipe) + fused/parallelized pre & out.

typedef _Float16 f16;
typedef f16 half8 __attribute__((ext_vector_type(8)));
typedef float f32x16 __attribute__((ext_vector_type(16)));

__device__ __forceinline__ unsigned int sortable_f32(float v) {
    unsigned int u = __float_as_uint(v);
    return (u & 0x80000000u) ? ~u : (u | 0x80000000u);
}

__device__ __forceinline__ void gload_lds16(const void* g, void* l) {
    __builtin_amdgcn_global_load_lds(
        (const __attribute__((address_space(1))) unsigned int*)g,
        (__attribute__((address_space(3))) unsigned int*)l, 16, 0, 0);
}

// ---- prep_e: split e (x 2^12) into swizzled fp16 planes + e2 + zero cand/negx2/loss
// e-plane layout (halves): ((kt*8+ci)*128 + kk)*32 + ((g ^ (kk&3))*8) + j, d=ci*32+g*8+j
__global__ void vq_prep_e(const float* __restrict__ ew, f16* __restrict__ ehi,
                          f16* __restrict__ elo, float* __restrict__ e2,
                          unsigned long long* __restrict__ cand,
                          float* __restrict__ negx2, float* __restrict__ loss_cell) {
    const int blk = blockIdx.x, tid = threadIdx.x;
    if (blk < 512) {
        const int t = blk * 256 + tid;          // 131072 = 4096 k * 32 groups
        const int k = t >> 5, g32 = t & 31;
        const float4 v0 = *(const float4*)(ew + k * 256 + g32 * 8);
        const float4 v1 = *(const float4*)(ew + k * 256 + g32 * 8 + 4);
        const float vf[8] = {v0.x, v0.y, v0.z, v0.w, v1.x, v1.y, v1.z, v1.w};
        half8 h1, h2;
#pragma unroll
        for (int j = 0; j < 8; ++j) {
            const float v = vf[j] * 4096.0f;    // exact (power of 2)
            const f16 a = (f16)v;
            const f16 b = (f16)(v - (float)a);  // exact in fp32
            h1[j] = a; h2[j] = b;
        }
        const int kt = k >> 7, kk = k & 127, ci = g32 >> 2, g = g32 & 3;
        const long off = ((long)((kt * 8 + ci) * 128 + kk)) * 32 + ((g ^ (kk & 3)) * 8);
        *(half8*)(ehi + off) = h1;
        *(half8*)(elo + off) = h2;
    } else if (blk < 528) {
        const int k = (blk - 512) * 256 + tid;  // e2, bit-identical order to R1/R2
        const float4* row = (const float4*)(ew + k * 256);
        float s = 0.0f;
#pragma unroll 8
        for (int i = 0; i < 64; ++i) {
            float4 v = row[i];
            s += v.x * v.x + v.y * v.y + v.z * v.z + v.w * v.w;
        }
        e2[k] = s;
    } else {
        const int z = (blk - 528) * 256 + tid;  // 8192
        cand[z] = 0ull;
        negx2[z] = 0.0f;
        if (z == 0) *loss_cell = 0.0f;
    }
}

// ---- prep_x: transpose+split x into swizzled fp16 planes; negx2 via atomic partials
// x-plane layout (halves): ((mt256*8+ci)*256 + mm)*32 + ((g ^ (mm&3))*8) + j
__global__ void vq_prep_x(const float* __restrict__ x, f16* __restrict__ xhi,
                          f16* __restrict__ xlo, float* __restrict__ negx2) {
    __shared__ float xs[32][132];
    const int tid = threadIdx.x;
    const int ci = blockIdx.x, mt = blockIdx.y;        // mt: 128-row tile, 0..63
    const int b = mt >> 3, n0 = (mt & 7) * 128, c0 = ci * 32;
#pragma unroll
    for (int it = 0; it < 4; ++it) {
        const int idx = tid + it * 256;
        const int cc = idx >> 5, nn4 = idx & 31;
        float4 v = *(const float4*)(x + b * 262144 + (c0 + cc) * 1024 + n0 + nn4 * 4);
        *(float4*)&xs[cc][nn4 * 4] = v;
    }
    __syncthreads();
    const int mt256 = mt >> 1;
    float sq = 0.0f;
    int mm_g = 0;
#pragma unroll
    for (int it = 0; it < 2; ++it) {
        const int idx = tid + it * 256;
        const int mm = idx & 127, g = idx >> 7;
        mm_g = mm;
        half8 h1, h2;
#pragma unroll
        for (int j = 0; j < 8; ++j) {
            const float v = xs[g * 8 + j][mm];
            sq += v * v;
            const f16 a = (f16)v;
            const f16 bb = (f16)(v - (float)a);
            h1[j] = a; h2[j] = bb;
        }
        const int mm256 = (mt & 1) * 128 + mm;
        const long off = ((long)((mt256 * 8 + ci) * 256 + mm256)) * 32 + ((g ^ (mm256 & 3)) * 8);
        *(half8*)(xhi + off) = h1;
        *(half8*)(xlo + off) = h2;
    }
    atomicAdd(&negx2[mt * 128 + mm_g], -sq);  // per-row uniform shift: argmax-safe
}

// ---- split-fp16 MFMA distance GEMM (32x32x16), 256m x 128k block, 4 waves 2x2
__launch_bounds__(256, 2)
__global__ void vq_gemm(const f16* __restrict__ xhi, const f16* __restrict__ xlo,
                        const f16* __restrict__ ehi, const f16* __restrict__ elo,
                        const float* __restrict__ e2, const float* __restrict__ negx2,
                        unsigned long long* __restrict__ cand) {
    // halves: xh [0,8192) 256x32 | xl [8192,16384) | eh [16384,20480) 128x32 | el [20480,24576)
    __shared__ __align__(16) f16 lds[24576];   // 48 KB
    const int tid = threadIdx.x;
    const int kt = blockIdx.x, mt = blockIdx.y;
    const int lane = tid & 63, wave = tid >> 6;
    const int wm = wave >> 1, wk = wave & 1;
    const int l31 = lane & 31, hl = lane >> 5;

    const f16* gxh = xhi + (size_t)(mt * 8) * 8192;
    const f16* gxl = xlo + (size_t)(mt * 8) * 8192;
    const f16* geh = ehi + (size_t)(kt * 8) * 4096;
    const f16* gel = elo + (size_t)(kt * 8) * 4096;

    f32x16 acc[4][2] = {};

    int aoff[4][2], boff[2][2];
#pragma unroll
    for (int i = 0; i < 4; ++i) {
        const int mr = wm * 128 + i * 32 + l31;
#pragma unroll
        for (int ks = 0; ks < 2; ++ks)
            aoff[i][ks] = mr * 32 + (((ks * 2 + hl) ^ (mr & 3)) * 8);
    }
#pragma unroll
    for (int j = 0; j < 2; ++j) {
        const int kr = wk * 64 + j * 32 + l31;
#pragma unroll
        for (int ks = 0; ks < 2; ++ks)
            boff[j][ks] = 16384 + kr * 32 + (((ks * 2 + hl) ^ (kr & 3)) * 8);
    }

    for (int ci = 0; ci < 8; ++ci) {
        __syncthreads();
        const int t8 = tid * 8;
        char* wb = (char*)lds + (tid >> 6) * 1024;   // wave-uniform dst base
#pragma unroll
        for (int p = 0; p < 4; ++p) gload_lds16(gxh + ci * 8192 + p * 2048 + t8, wb + p * 4096);
#pragma unroll
        for (int p = 0; p < 4; ++p) gload_lds16(gxl + ci * 8192 + p * 2048 + t8, wb + 16384 + p * 4096);
#pragma unroll
        for (int p = 0; p < 2; ++p) gload_lds16(geh + ci * 4096 + p * 2048 + t8, wb + 32768 + p * 4096);
#pragma unroll
        for (int p = 0; p < 2; ++p) gload_lds16(gel + ci * 4096 + p * 2048 + t8, wb + 40960 + p * 4096);
        __syncthreads();

#pragma unroll
        for (int ks = 0; ks < 2; ++ks) {
            half8 ah[4], al[4], bh[2], bl[2];
#pragma unroll
            for (int i = 0; i < 4; ++i) {
                ah[i] = *(const half8*)&lds[aoff[i][ks]];
                al[i] = *(const half8*)&lds[8192 + aoff[i][ks]];
            }
#pragma unroll
            for (int j = 0; j < 2; ++j) {
                bh[j] = *(const half8*)&lds[boff[j][ks]];
                bl[j] = *(const half8*)&lds[4096 + boff[j][ks]];
            }
#pragma unroll
            for (int i = 0; i < 4; ++i)
#pragma unroll
                for (int j = 0; j < 2; ++j) {
                    acc[i][j] = __builtin_amdgcn_mfma_f32_32x32x16_f16(ah[i], bh[j], acc[i][j], 0, 0, 0);
                    acc[i][j] = __builtin_amdgcn_mfma_f32_32x32x16_f16(ah[i], bl[j], acc[i][j], 0, 0, 0);
                    acc[i][j] = __builtin_amdgcn_mfma_f32_32x32x16_f16(al[i], bh[j], acc[i][j], 0, 0, 0);
                }
        }
    }

    // epilogue; 32x32 C layout: col = lane&31, row = (r&3) + 8*(r>>2) + 4*hl
    const int m0g = mt * 256 + wm * 128;
    const int k0g = kt * 128 + wk * 64;
#pragma unroll
    for (int i = 0; i < 4; ++i) {
#pragma unroll
        for (int r = 0; r < 16; ++r) {
            const int row = (r & 3) + 8 * (r >> 2) + 4 * hl;
            const int mg = m0g + i * 32 + row;
            const float A = negx2[mg];
            unsigned long long bk = 0ull;
#pragma unroll
            for (int j = 0; j < 2; ++j) {
                const int kg = k0g + j * 32 + l31;
                const float t1 = A - e2[kg];                      // rounding 1
                const float dist = t1 + acc[i][j][r] * 0x1p-11f;  // exact scale; rounding 2
                const unsigned long long key =
                    ((unsigned long long)sortable_f32(dist) << 32)
                    | (unsigned long long)(unsigned int)(4095 - kg);
                if (key > bk) bk = key;
            }
#pragma unroll
            for (int mask = 1; mask <= 16; mask <<= 1) {
                const unsigned long long o = __shfl_xor(bk, mask, 64);
                if (o > bk) bk = o;
            }
            if (l31 == r) atomicMax(&cand[mg], bk);
        }
    }
}

// ---- final: gather, transposed store, loss, embed_ind (512 blocks)
__global__ void vq_out(const float* __restrict__ x, const float* __restrict__ ew,
                       const unsigned long long* __restrict__ cand,
                       float* __restrict__ out) {
    __shared__ int sidx[64];
    __shared__ float wsum[4];
    const int tid = threadIdx.x;
    const int r0 = blockIdx.x * 64;
    const int cq0 = blockIdx.y * 64;
    const int b = r0 >> 10, n0 = r0 & 1023;

    if (tid < 64) {
        const int r = r0 + tid;
        const unsigned long long bk = cand[r];
        const int idx = 4095 - (int)(unsigned int)(bk & 0xFFFFFFFFull);
        sidx[tid] = idx;
        if (blockIdx.y == 0) out[2097153 + r] = (float)idx;
    }
    __syncthreads();

    const int nn = tid & 63, cq = tid >> 6;
    const int myidx = sidx[nn];
    float lsum = 0.0f;
#pragma unroll 4
    for (int cb = 0; cb < 16; ++cb) {
        const int c = cq0 + cb * 4 + cq;
        const float ve = ew[myidx * 256 + c];
        const long off = (long)b * 262144 + (c << 10) + n0 + nn;
        const float vx = x[off];
        out[off] = ve;
        const float d = ve - vx;
        lsum += d * d;
    }
#pragma unroll
    for (int off = 32; off > 0; off >>= 1)
        lsum += __shfl_down(lsum, off, 64);
    const int lane = tid & 63, w = tid >> 6;
    if (lane == 0) wsum[w] = lsum;
    __syncthreads();
    if (tid == 0) {
        const float s = wsum[0] + wsum[1] + wsum[2] + wsum[3];
        atomicAdd(&out[2097152], 1.25f * (s / 2097152.0f));
    }
}

extern "C" void kernel_launch(void* const* d_in, const int* in_sizes, int n_in,
                              void* d_out, int out_size, void* d_ws, size_t ws_size,
                              hipStream_t stream) {
    const float* x  = (const float*)d_in[0];
    const float* ew = (const float*)d_in[1];
    float* out = (float*)d_out;

    float* e2 = (float*)d_ws;                                              // 16 KB
    float* negx2 = e2 + 4096;                                              // 32 KB
    unsigned long long* cand = (unsigned long long*)((char*)d_ws + 49152); // 64 KB
    f16* ehi = (f16*)((char*)d_ws + 114688);                               // 2 MB
    f16* elo = (f16*)((char*)d_ws + 114688 + 2097152);                     // 2 MB
    f16* xhi = (f16*)out;                                                  // x_q region scratch
    f16* xlo = (f16*)(out + 1048576);

    vq_prep_e<<<560, 256, 0, stream>>>(ew, ehi, elo, e2, cand, negx2, out + 2097152);
    vq_prep_x<<<dim3(8, 64), 256, 0, stream>>>(x, xhi, xlo, negx2);
    vq_gemm<<<dim3(32, 32), 256, 0, stream>>>(xhi, xlo, ehi, elo, e2, negx2, cand);
    vq_out<<<dim3(128, 4), 256, 0, stream>>>(x, ew, cand, out);
}